// Round 8
// baseline (647.362 us; speedup 1.0000x reference)
//
#include <hip/hip_runtime.h>
#include <math.h>

#define BB 64
#define T_SUB 512
#define WW 256
#define DD 768
#define HH 20
#define CAP_DIM 10
#define IN_DIM 778
#define KPAD 800
#define G4 80     // 4*H
#define NOUT 160  // both directions fused

#define PROBE_REP 4   // R8 probe: in-kernel repetition for gemm+lstm timing

typedef _Float16 f16x8 __attribute__((ext_vector_type(8)));
typedef _Float16 f16x4 __attribute__((ext_vector_type(4)));
typedef float f32x4 __attribute__((ext_vector_type(4)));

// ws layout (bytes):
//   wpad : [160][800] f16   @ 0          (256,000 B)
//   seg  : int2[16384]      @ 256,000    (131,072 B)
//   x    : [16384][800] f16 @ 387,072    (26,214,400 B)
//   gpre : [16384][160] f32 @ 26,601,472 (10,485,760 B) -- columns PERMUTED
#define WP_OFF   ((size_t)0)
#define SEG_OFF  ((size_t)256000)
#define X_OFF    ((size_t)387072)
#define GP_OFF   ((size_t)26601472)

// ---------------- K0: pad weights (blocks 0..159) + segment search (160..223)
__global__ __launch_bounds__(256) void k_prep(
    const float* __restrict__ wf, const float* __restrict__ wb,
    const int* __restrict__ b2t,
    _Float16* __restrict__ wp, int2* __restrict__ seg)
{
    int blk = blockIdx.x;
    if (blk < NOUT) {
        int j = blk;
        const float* src = (j < G4) ? (wf + (size_t)j * IN_DIM)
                                    : (wb + (size_t)(j - G4) * IN_DIM);
        for (int k = threadIdx.x; k < KPAD; k += 256)
            wp[(size_t)j * KPAD + k] = (k < IN_DIM) ? (_Float16)src[k] : (_Float16)0.f;
    } else {
        int b = blk - NOUT, w = threadIdx.x;
        const int* row = b2t + (size_t)b * T_SUB;
        int lo = 0, hi = T_SUB;
        while (lo < hi) { int m = (lo + hi) >> 1; if (row[m] < w) lo = m + 1; else hi = m; }
        int lo2 = lo, hi2 = T_SUB;
        while (lo2 < hi2) { int m = (lo2 + hi2) >> 1; if (row[m] < w + 1) lo2 = m + 1; else hi2 = m; }
        seg[(size_t)b * WW + w] = make_int2(lo, lo2 - lo);
    }
}

// ---------------- K1: streaming mean -> fp16 x. One thread per 4 output dims.
__global__ __launch_bounds__(256) void k_mean(
    const float* __restrict__ hiddens, const int2* __restrict__ seg,
    const int* __restrict__ cap_inds, const float* __restrict__ cap_table,
    _Float16* __restrict__ x)
{
    int idx = blockIdx.x * 256 + threadIdx.x;   // 16384*200 total
    int d4 = idx % 200;
    int bw = idx / 200;
    int b = bw >> 8;
    f16x4 r;
    if (d4 < 192) {
        int2 sg = seg[bw];
        int lo = sg.x, cnt = sg.y;
        const size_t LSTR = (size_t)BB * (T_SUB + 1) * DD;
        const float* base = hiddens + ((size_t)b * (T_SUB + 1) + lo + 1) * DD + d4 * 4;
        float ax = 0.f, ay = 0.f, az = 0.f, aw = 0.f;
        if (cnt == 2) {
#pragma unroll
            for (int l = 0; l < 3; ++l) {
                float4 v0 = *(const float4*)(base + l * LSTR);
                float4 v1 = *(const float4*)(base + l * LSTR + DD);
                ax += v0.x + v1.x; ay += v0.y + v1.y;
                az += v0.z + v1.z; aw += v0.w + v1.w;
            }
        } else {
            for (int l = 0; l < 3; ++l)
                for (int ti = 0; ti < cnt; ++ti) {
                    float4 v = *(const float4*)(base + l * LSTR + (size_t)ti * DD);
                    ax += v.x; ay += v.y; az += v.z; aw += v.w;
                }
        }
        float inv = 1.0f / (3.0f * (float)(cnt > 0 ? cnt : 1));
        r[0] = (_Float16)(ax * inv); r[1] = (_Float16)(ay * inv);
        r[2] = (_Float16)(az * inv); r[3] = (_Float16)(aw * inv);
    } else {
        int ci = cap_inds[bw];
#pragma unroll
        for (int q = 0; q < 4; q++) {
            int c = (d4 - 192) * 4 + q;   // col 768+c
            r[q] = (c < CAP_DIM) ? (_Float16)cap_table[ci * CAP_DIM + c] : (_Float16)0.f;
        }
    }
    *(f16x4*)(x + (size_t)bw * KPAD + d4 * 4) = r;
}

// ---------------- K2: barrier-free MFMA fp16 GEMM, operands from global -----
// PROBE: whole K-loop repeated PROBE_REP times (idempotent; acc re-zeroed).
#define LOADAB(A, Bv, K0) do {                                                  \
    A = *(const f16x8*)(ap + (K0));                                             \
    _Pragma("unroll")                                                           \
    for (int nf = 0; nf < 10; nf++)                                             \
        Bv[nf] = *(const f16x8*)(bp + (size_t)nf * 16 * KPAD + (K0));           \
} while (0)
#define DOMFMA(A, Bv) do {                                                      \
    _Pragma("unroll")                                                           \
    for (int nf = 0; nf < 10; nf++)                                             \
        acc[nf] = __builtin_amdgcn_mfma_f32_16x16x32_f16(A, Bv[nf], acc[nf], 0, 0, 0); \
} while (0)

__global__ __launch_bounds__(256) void k_gemm(
    const _Float16* __restrict__ x, const _Float16* __restrict__ wp,
    float* __restrict__ gpre)
{
    int t = threadIdx.x, wv = t >> 6, lane = t & 63;
    int row  = blockIdx.x * 64 + wv * 16 + (lane & 15);
    int koff = (lane >> 4) * 8;
    const _Float16* ap = x + (size_t)row * KPAD + koff;
    const _Float16* bp = wp + (size_t)(lane & 15) * KPAD + koff;
    f32x4 acc[10];

    for (int rep = 0; rep < PROBE_REP; ++rep) {
        asm volatile("" ::: "memory");   // block cross-rep CSE of loads
#pragma unroll
        for (int i = 0; i < 10; i++)
#pragma unroll
            for (int r = 0; r < 4; r++) acc[i][r] = 0.f;
        f16x8 a0v, a1v, b0v[10], b1v[10];
        LOADAB(a0v, b0v, 0);
        int k0 = 0;
        for (int it = 0; it < 12; ++it, k0 += 64) {
            LOADAB(a1v, b1v, k0 + 32);
            DOMFMA(a0v, b0v);
            LOADAB(a0v, b0v, k0 + 64);
            DOMFMA(a1v, b1v);
        }
        DOMFMA(a0v, b0v);   // k0 == 768 chunk
    }

    // C/D: col = lane&15, row = (lane>>4)*4 + reg [m89-verified].
    // Permute cols so lstm lane j reads (gate j, gate j+40) as one float2.
    int orow = blockIdx.x * 64 + wv * 16 + (lane >> 4) * 4;
    int ocol = lane & 15;
#pragma unroll
    for (int nf = 0; nf < 10; nf++) {
        int col = nf * 16 + ocol;
        int dir = (col >= G4) ? 1 : 0;
        int g = col - dir * G4;
        int pcol = dir * G4 + (g % 40) * 2 + (g / 40);
#pragma unroll
        for (int r = 0; r < 4; r++)
            gpre[(size_t)(orow + r) * NOUT + pcol] = acc[nf][r];
    }
}

// ---------------- K3: recurrent LSTM, LDS-staged gpre, chunked ping-pong ----
// PROBE: whole recurrence repeated PROBE_REP times (h,c re-initialized).
__device__ __forceinline__ float fsig(float v) { return 1.f / (1.f + __expf(-v)); }
__device__ __forceinline__ float ftanh(float v) { return 2.f / (1.f + __expf(-2.f * v)) - 1.f; }

__global__ __launch_bounds__(256) void k_lstm(
    const float* __restrict__ gpre,
    const float* __restrict__ whh_f, const float* __restrict__ whh_b,
    const float* __restrict__ bias_f, const float* __restrict__ bias_b,
    float* __restrict__ out)
{
    __shared__ float gbuf[2][64 * G4];   // 2 x 20 KB ping-pong
    int dir  = blockIdx.x >> 6;
    int b    = blockIdx.x & 63;
    int t    = threadIdx.x;
    int wv   = t >> 6;
    int lane = t & 63;
    const float* gsrc = gpre + (size_t)b * WW * NOUT + dir * G4;

    const float* whh  = dir ? whh_b  : whh_f;
    const float* bias = dir ? bias_b : bias_f;
    int g0 = (lane < 40) ? lane : 39;
    int g1 = g0 + 40;
    float w0[HH], w1[HH], b0 = 0.f, b1 = 0.f;
    if (wv == 0) {
#pragma unroll
        for (int k = 0; k < HH; k++) {
            w0[k] = whh[g0 * HH + k];
            w1[k] = whh[g1 * HH + k];
        }
        b0 = bias[g0]; b1 = bias[g1];
    }

    for (int rep = 0; rep < PROBE_REP; ++rep) {
        asm volatile("" ::: "memory");
        // stage chunk 0 into buf 0 (all 4 waves; 1280 float4 items)
        {
            int base = dir ? 192 : 0;
            for (int f = t; f < 1280; f += 256) {
                int row = f / 20, q = f % 20;
                float4 v = *(const float4*)(gsrc + (size_t)(base + row) * NOUT + q * 4);
                *(float4*)(&gbuf[0][row * G4 + q * 4]) = v;
            }
        }
        __syncthreads();

        float h = 0.f, c = 0.f;
        int w = dir ? (WW - 1) : 0;
        int stepd = dir ? -1 : 1;

        for (int ch = 0; ch < 4; ++ch) {
            int cb = ch & 1;
            if (wv > 0) {
                if (ch + 1 < 4) {
                    int nbase = dir ? (192 - (ch + 1) * 64) : (ch + 1) * 64;
                    for (int f = t - 64; f < 1280; f += 192) {
                        int row = f / 20, q = f % 20;
                        float4 v = *(const float4*)(gsrc + (size_t)(nbase + row) * NOUT + q * 4);
                        *(float4*)(&gbuf[cb ^ 1][row * G4 + q * 4]) = v;
                    }
                }
            } else {
                int base = dir ? (192 - ch * 64) : ch * 64;
                float2 pre = *(const float2*)(&gbuf[cb][(w - base) * G4 + g0 * 2]);
                for (int sl = 0; sl < 64; ++sl) {
                    int wn = w + stepd;
                    float2 nxt = make_float2(0.f, 0.f);
                    if (sl < 63)
                        nxt = *(const float2*)(&gbuf[cb][(wn - base) * G4 + g0 * 2]);
                    float s00 = 0.f, s01 = 0.f, s10 = 0.f, s11 = 0.f;
#pragma unroll
                    for (int k = 0; k < 10; k++) {
                        float hv  = __shfl(h, k, 64);
                        float hv2 = __shfl(h, k + 10, 64);
                        s00 = fmaf(hv,  w0[k],      s00);
                        s10 = fmaf(hv,  w1[k],      s10);
                        s01 = fmaf(hv2, w0[k + 10], s01);
                        s11 = fmaf(hv2, w1[k + 10], s11);
                    }
                    float a0 = pre.x + b0 + s00 + s01;
                    float a1 = pre.y + b1 + s10 + s11;
                    int src = (lane % 20) + 20;
                    float fv = __shfl(a0, src, 64);
                    float ov = __shfl(a1, src, 64);
                    if (lane < HH) {
                        c = fsig(fv) * c + fsig(a0) * ftanh(a1);
                        h = fsig(ov) * ftanh(c);
                        out[((size_t)b * WW + w) * (2 * HH) + dir * HH + lane] = h;
                    }
                    pre = nxt;
                    w = wn;
                }
            }
            __syncthreads();
        }
    }
}

extern "C" void kernel_launch(void* const* d_in, const int* in_sizes, int n_in,
                              void* d_out, int out_size, void* d_ws, size_t ws_size,
                              hipStream_t stream) {
    const float* hiddens   = (const float*)d_in[0];
    const int*   bert2toks = (const int*)d_in[1];
    const int*   cap_inds  = (const int*)d_in[2];
    const float* cap_table = (const float*)d_in[3];
    const float* w_ih_f    = (const float*)d_in[4];
    const float* w_hh_f    = (const float*)d_in[5];
    const float* b_f       = (const float*)d_in[6];
    const float* w_ih_b    = (const float*)d_in[7];
    const float* w_hh_b    = (const float*)d_in[8];
    const float* b_b       = (const float*)d_in[9];
    float* out = (float*)d_out;

    _Float16* wpad = (_Float16*)((char*)d_ws + WP_OFF);
    int2*     seg  = (int2*)((char*)d_ws + SEG_OFF);
    _Float16* x    = (_Float16*)((char*)d_ws + X_OFF);
    float*    gpre = (float*)((char*)d_ws + GP_OFF);

    k_prep<<<NOUT + BB, 256, 0, stream>>>(w_ih_f, w_ih_b, bert2toks, wpad, seg);
    k_mean<<<(BB * WW * 200) / 256, 256, 0, stream>>>(hiddens, seg, cap_inds, cap_table, x);
    k_gemm<<<(BB * WW) / 64, 256, 0, stream>>>(x, wpad, gpre);
    k_lstm<<<128, 256, 0, stream>>>(gpre, w_hh_f, w_hh_b, b_f, b_b, out);
}

// Round 10
// 168.451 us; speedup vs baseline: 3.8430x; 3.8430x over previous
//
#include <hip/hip_runtime.h>
#include <math.h>

#define BB 64
#define T_SUB 512
#define WW 256
#define DD 768
#define HH 20
#define CAP_DIM 10
#define IN_DIM 778
#define KPAD 800
#define G4 80     // 4*H
#define NOUT 160  // both directions fused

typedef _Float16 f16x8 __attribute__((ext_vector_type(8)));
typedef _Float16 f16x4 __attribute__((ext_vector_type(4)));
typedef float f32x4 __attribute__((ext_vector_type(4)));
typedef unsigned int uint2v __attribute__((ext_vector_type(2)));

// ws layout (bytes):
//   wpad : [160][800] f16   @ 0          (256,000 B)
//   seg  : int2[16384]      @ 256,000    (131,072 B)
//   x    : [16384][800] f16 @ 387,072    (26,214,400 B)
//   gpre : [16384][160] f32 @ 26,601,472 (10,485,760 B) -- cols PERMUTED, bias folded
#define WP_OFF   ((size_t)0)
#define SEG_OFF  ((size_t)256000)
#define X_OFF    ((size_t)387072)
#define GP_OFF   ((size_t)26601472)

// ---------------- K0: pad weights (blocks 0..159) + segment search (160..223)
__global__ __launch_bounds__(256) void k_prep(
    const float* __restrict__ wf, const float* __restrict__ wb,
    const int* __restrict__ b2t,
    _Float16* __restrict__ wp, int2* __restrict__ seg)
{
    int blk = blockIdx.x;
    if (blk < NOUT) {
        int j = blk;
        const float* src = (j < G4) ? (wf + (size_t)j * IN_DIM)
                                    : (wb + (size_t)(j - G4) * IN_DIM);
        for (int k = threadIdx.x; k < KPAD; k += 256)
            wp[(size_t)j * KPAD + k] = (k < IN_DIM) ? (_Float16)src[k] : (_Float16)0.f;
    } else {
        int b = blk - NOUT, w = threadIdx.x;
        const int* row = b2t + (size_t)b * T_SUB;
        int lo = 0, hi = T_SUB;
        while (lo < hi) { int m = (lo + hi) >> 1; if (row[m] < w) lo = m + 1; else hi = m; }
        int lo2 = lo, hi2 = T_SUB;
        while (lo2 < hi2) { int m = (lo2 + hi2) >> 1; if (row[m] < w + 1) lo2 = m + 1; else hi2 = m; }
        seg[(size_t)b * WW + w] = make_int2(lo, lo2 - lo);
    }
}

// ---------------- K1: streaming mean -> fp16 x. One thread per 4 output dims.
__global__ __launch_bounds__(256) void k_mean(
    const float* __restrict__ hiddens, const int2* __restrict__ seg,
    const int* __restrict__ cap_inds, const float* __restrict__ cap_table,
    _Float16* __restrict__ x)
{
    int idx = blockIdx.x * 256 + threadIdx.x;   // 16384*200 total
    int d4 = idx % 200;
    int bw = idx / 200;
    int b = bw >> 8;
    f16x4 r;
    if (d4 < 192) {
        int2 sg = seg[bw];
        int lo = sg.x, cnt = sg.y;
        const size_t LSTR = (size_t)BB * (T_SUB + 1) * DD;
        const float* base = hiddens + ((size_t)b * (T_SUB + 1) + lo + 1) * DD + d4 * 4;
        float ax = 0.f, ay = 0.f, az = 0.f, aw = 0.f;
        if (cnt == 2) {
#pragma unroll
            for (int l = 0; l < 3; ++l) {
                float4 v0 = *(const float4*)(base + l * LSTR);
                float4 v1 = *(const float4*)(base + l * LSTR + DD);
                ax += v0.x + v1.x; ay += v0.y + v1.y;
                az += v0.z + v1.z; aw += v0.w + v1.w;
            }
        } else {
            for (int l = 0; l < 3; ++l)
                for (int ti = 0; ti < cnt; ++ti) {
                    float4 v = *(const float4*)(base + l * LSTR + (size_t)ti * DD);
                    ax += v.x; ay += v.y; az += v.z; aw += v.w;
                }
        }
        float inv = 1.0f / (3.0f * (float)(cnt > 0 ? cnt : 1));
        r[0] = (_Float16)(ax * inv); r[1] = (_Float16)(ay * inv);
        r[2] = (_Float16)(az * inv); r[3] = (_Float16)(aw * inv);
    } else {
        int ci = cap_inds[bw];
#pragma unroll
        for (int q = 0; q < 4; q++) {
            int c = (d4 - 192) * 4 + q;   // col 768+c
            r[q] = (c < CAP_DIM) ? (_Float16)cap_table[ci * CAP_DIM + c] : (_Float16)0.f;
        }
    }
    *(f16x4*)(x + (size_t)bw * KPAD + d4 * 4) = r;
}

// ---------------- K2: barrier-free MFMA fp16 GEMM, operands from global -----
#define LOADAB(A, Bv, K0) do {                                                  \
    A = *(const f16x8*)(ap + (K0));                                             \
    _Pragma("unroll")                                                           \
    for (int nf = 0; nf < 10; nf++)                                             \
        Bv[nf] = *(const f16x8*)(bp + (size_t)nf * 16 * KPAD + (K0));           \
} while (0)
#define DOMFMA(A, Bv) do {                                                      \
    _Pragma("unroll")                                                           \
    for (int nf = 0; nf < 10; nf++)                                             \
        acc[nf] = __builtin_amdgcn_mfma_f32_16x16x32_f16(A, Bv[nf], acc[nf], 0, 0, 0); \
} while (0)

__global__ __launch_bounds__(256) void k_gemm(
    const _Float16* __restrict__ x, const _Float16* __restrict__ wp,
    const float* __restrict__ bias_f, const float* __restrict__ bias_b,
    float* __restrict__ gpre)
{
    int t = threadIdx.x, wv = t >> 6, lane = t & 63;
    int row  = blockIdx.x * 64 + wv * 16 + (lane & 15);
    int koff = (lane >> 4) * 8;
    const _Float16* ap = x + (size_t)row * KPAD + koff;
    const _Float16* bp = wp + (size_t)(lane & 15) * KPAD + koff;
    f32x4 acc[10];
#pragma unroll
    for (int i = 0; i < 10; i++)
#pragma unroll
        for (int r = 0; r < 4; r++) acc[i][r] = 0.f;

    f16x8 a0v, a1v, b0v[10], b1v[10];
    LOADAB(a0v, b0v, 0);
    int k0 = 0;
    for (int it = 0; it < 12; ++it, k0 += 64) {
        LOADAB(a1v, b1v, k0 + 32);
        DOMFMA(a0v, b0v);
        LOADAB(a0v, b0v, k0 + 64);
        DOMFMA(a1v, b1v);
    }
    DOMFMA(a0v, b0v);   // k0 == 768 chunk

    // C/D: col = lane&15, row = (lane>>4)*4 + reg [m89-verified].
    // Permute cols (dir*80+g -> dir*80 + (g%40)*2 + g/40) and fold bias:
    //   (i_j,g_j) -> (2j,2j+1), (f_j,o_j) -> (40+2j,41+2j)
    int orow = blockIdx.x * 64 + wv * 16 + (lane >> 4) * 4;
    int ocol = lane & 15;
#pragma unroll
    for (int nf = 0; nf < 10; nf++) {
        int col = nf * 16 + ocol;
        int dir = (col >= G4) ? 1 : 0;
        int g = col - dir * G4;
        int pcol = dir * G4 + (g % 40) * 2 + (g / 40);
        float bv = (dir ? bias_b : bias_f)[g];
#pragma unroll
        for (int r = 0; r < 4; r++)
            gpre[(size_t)(orow + r) * NOUT + pcol] = acc[nf][r] + bv;
    }
}

// ---------------- K3: recurrent LSTM — no ds_bpermute in the chain ----------
// grid 128 (dir*64+b), block 256 (4 waves; wave 0 computes, waves 1-3 stage).
// Lane layout (wave 0): lanes j<20 own (f_j,o_j) + state h_j,c_j;
//                       lanes 32+j own (i_j,g_j).
// h-broadcast: v_readlane (VALU). Cross-half move of p=sig(i)*tanh(g):
// permlane32_swap (VALU). FIX vs R9: partner value extracted as
// r[0]^r[1]^own — with swap(a,a), {r[0],r[1]} = {own, partner} as a set
// under either dst.hi<->src.lo convention; XOR recovers partner exactly.
__device__ __forceinline__ float xchg32(float v) {
    unsigned int a = __float_as_uint(v);
    uint2v r = __builtin_amdgcn_permlane32_swap(a, a, false, false);
    return __uint_as_float(r[0] ^ r[1] ^ a);   // partner lane's value (lane ^ 32)
}

__global__ __launch_bounds__(256) void k_lstm(
    const float* __restrict__ gpre,
    const float* __restrict__ whh_f, const float* __restrict__ whh_b,
    float* __restrict__ out)
{
    __shared__ float gbuf[2][64 * G4];   // 2 x 20 KB ping-pong
    int dir  = blockIdx.x >> 6;
    int b    = blockIdx.x & 63;
    int t    = threadIdx.x;
    int wv   = t >> 6;
    int lane = t & 63;
    const float* gsrc = gpre + (size_t)b * WW * NOUT + dir * G4;

    // initial stage: chunk 0 into buf 0 (all 4 waves)
    {
        int base = dir ? 192 : 0;
        for (int f = t; f < 1280; f += 256) {
            int row = f / 20, q = f % 20;
            float4 v = *(const float4*)(gsrc + (size_t)(base + row) * NOUT + q * 4);
            *(float4*)(&gbuf[0][row * G4 + q * 4]) = v;
        }
    }

    const float* whh = dir ? whh_b : whh_f;
    int j = lane & 31; if (j > 19) j = 19;   // clamp idle lanes
    bool low = lane < 32;
    float mm = low ? 1.f : 2.f;
    float aa = low ? 0.f : -1.f;
    int coff = low ? (40 + 2 * j) : (2 * j);  // (f,o) pair | (i,g) pair
    float w0[HH], w1[HH];
    if (wv == 0) {
        int r0 = low ? (20 + j) : j;          // f row | i row
        int r1 = low ? (60 + j) : (40 + j);   // o row | g row
#pragma unroll
        for (int k = 0; k < HH; k++) {
            w0[k] = whh[r0 * HH + k];
            w1[k] = whh[r1 * HH + k];
        }
    }
    __syncthreads();

    float h = 0.f, c = 0.f;
    int w = dir ? (WW - 1) : 0;
    int stepd = dir ? -1 : 1;

    for (int ch = 0; ch < 4; ++ch) {
        int cb = ch & 1;
        if (wv > 0) {
            if (ch + 1 < 4) {
                int nbase = dir ? (192 - (ch + 1) * 64) : (ch + 1) * 64;
                for (int f = t - 64; f < 1280; f += 192) {
                    int row = f / 20, q = f % 20;
                    float4 v = *(const float4*)(gsrc + (size_t)(nbase + row) * NOUT + q * 4);
                    *(float4*)(&gbuf[cb ^ 1][row * G4 + q * 4]) = v;
                }
            }
        } else {
            int base = dir ? (192 - ch * 64) : ch * 64;
            float2 pre = *(const float2*)(&gbuf[cb][(w - base) * G4 + coff]);
            for (int sl = 0; sl < 64; ++sl) {
                int wn = w + stepd;
                float2 nxt = make_float2(0.f, 0.f);
                if (sl < 63)
                    nxt = *(const float2*)(&gbuf[cb][(wn - base) * G4 + coff]);
                // two dots of depth 20, split accumulators (chain 40 cyc)
                float a0a = pre.x, a0b = 0.f, a1a = pre.y, a1b = 0.f;
#pragma unroll
                for (int k = 0; k < 10; k++) {
                    float hk  = __uint_as_float(__builtin_amdgcn_readlane(__float_as_uint(h), k));
                    float hk2 = __uint_as_float(__builtin_amdgcn_readlane(__float_as_uint(h), k + 10));
                    a0a = fmaf(hk,  w0[k],      a0a);
                    a1a = fmaf(hk,  w1[k],      a1a);
                    a0b = fmaf(hk2, w0[k + 10], a0b);
                    a1b = fmaf(hk2, w1[k + 10], a1b);
                }
                float a0 = a0a + a0b, a1 = a1a + a1b;
                float u0 = 1.f / (1.f + __expf(-a0));          // sig(f) | sig(i)
                float uu = 1.f / (1.f + __expf(-mm * a1));
                float u1 = fmaf(uu, mm, aa);                   // sig(o) | tanh(g)
                float p  = u0 * u1;                            // (junk) | sig(i)*tanh(g)
                float ps = xchg32(p);                          // low lanes get high's p
                c = fmaf(u0, c, ps);                           // sig(f)*c + sig(i)*tanh(g)
                float tc = fmaf(2.f, 1.f / (1.f + __expf(-2.f * c)), -1.f); // tanh(c)
                h = u1 * tc;                                   // sig(o)*tanh(c)
                if (lane < HH)
                    out[((size_t)b * WW + w) * (2 * HH) + dir * HH + lane] = h;
                pre = nxt;
                w = wn;
            }
        }
        __syncthreads();
    }
}

extern "C" void kernel_launch(void* const* d_in, const int* in_sizes, int n_in,
                              void* d_out, int out_size, void* d_ws, size_t ws_size,
                              hipStream_t stream) {
    const float* hiddens   = (const float*)d_in[0];
    const int*   bert2toks = (const int*)d_in[1];
    const int*   cap_inds  = (const int*)d_in[2];
    const float* cap_table = (const float*)d_in[3];
    const float* w_ih_f    = (const float*)d_in[4];
    const float* w_hh_f    = (const float*)d_in[5];
    const float* b_f       = (const float*)d_in[6];
    const float* w_ih_b    = (const float*)d_in[7];
    const float* w_hh_b    = (const float*)d_in[8];
    const float* b_b       = (const float*)d_in[9];
    float* out = (float*)d_out;

    _Float16* wpad = (_Float16*)((char*)d_ws + WP_OFF);
    int2*     seg  = (int2*)((char*)d_ws + SEG_OFF);
    _Float16* x    = (_Float16*)((char*)d_ws + X_OFF);
    float*    gpre = (float*)((char*)d_ws + GP_OFF);

    k_prep<<<NOUT + BB, 256, 0, stream>>>(w_ih_f, w_ih_b, bert2toks, wpad, seg);
    k_mean<<<(BB * WW * 200) / 256, 256, 0, stream>>>(hiddens, seg, cap_inds, cap_table, x);
    k_gemm<<<(BB * WW) / 64, 256, 0, stream>>>(x, wpad, b_f, b_b, gpre);
    k_lstm<<<128, 256, 0, stream>>>(gpre, w_hh_f, w_hh_b, out);
}

// Round 11
// 160.947 us; speedup vs baseline: 4.0222x; 1.0466x over previous
//
#include <hip/hip_runtime.h>
#include <math.h>

#define BB 64
#define T_SUB 512
#define WW 256
#define DD 768
#define HH 20
#define CAP_DIM 10
#define IN_DIM 778
#define KPAD 800
#define G4 80     // 4*H
#define NOUT 160

typedef _Float16 f16x8 __attribute__((ext_vector_type(8)));
typedef float f32x4 __attribute__((ext_vector_type(4)));
typedef unsigned int uint2v __attribute__((ext_vector_type(2)));

// ws layout (bytes):
//   wpad : [160][800] f16   @ 0          (256,000 B)
//   seg  : int2[16384]      @ 256,000    (131,072 B)
//   x    : [16384][800] f16 @ 387,072    (26,214,400 B)
#define WP_OFF   ((size_t)0)
#define SEG_OFF  ((size_t)256000)
#define X_OFF    ((size_t)387072)

// ---------------- K0: pad weights (blocks 0..159) + segment search (160..223)
__global__ __launch_bounds__(256) void k_prep(
    const float* __restrict__ wf, const float* __restrict__ wb,
    const int* __restrict__ b2t,
    _Float16* __restrict__ wp, int2* __restrict__ seg)
{
    int blk = blockIdx.x;
    if (blk < NOUT) {
        int j = blk;
        const float* src = (j < G4) ? (wf + (size_t)j * IN_DIM)
                                    : (wb + (size_t)(j - G4) * IN_DIM);
        for (int k = threadIdx.x; k < KPAD; k += 256)
            wp[(size_t)j * KPAD + k] = (k < IN_DIM) ? (_Float16)src[k] : (_Float16)0.f;
    } else {
        int b = blk - NOUT, w = threadIdx.x;
        const int* row = b2t + (size_t)b * T_SUB;
        int lo = 0, hi = T_SUB;
        while (lo < hi) { int m = (lo + hi) >> 1; if (row[m] < w) lo = m + 1; else hi = m; }
        int lo2 = lo, hi2 = T_SUB;
        while (lo2 < hi2) { int m = (lo2 + hi2) >> 1; if (row[m] < w + 1) lo2 = m + 1; else hi2 = m; }
        seg[(size_t)b * WW + w] = make_int2(lo, lo2 - lo);
    }
}

// ---------------- K1: streaming mean -> fp16 x. One thread per 8 output dims.
// idx = bw*100 + d8; d8<96: mean of 3 layers x cnt tokens; d8 96..99: caps/pad.
__global__ __launch_bounds__(256) void k_mean(
    const float* __restrict__ hiddens, const int2* __restrict__ seg,
    const int* __restrict__ cap_inds, const float* __restrict__ cap_table,
    _Float16* __restrict__ x)
{
    int idx = blockIdx.x * 256 + threadIdx.x;   // 16384*100 total
    int d8 = idx % 100;
    int bw = idx / 100;
    int b = bw >> 8;
    f16x8 r;
    if (d8 < 96) {
        int2 sg = seg[bw];
        int lo = sg.x, cnt = sg.y;
        const size_t LSTR = (size_t)BB * (T_SUB + 1) * DD;
        const float* base = hiddens + ((size_t)b * (T_SUB + 1) + lo + 1) * DD + d8 * 8;
        float a[8];
#pragma unroll
        for (int q = 0; q < 8; q++) a[q] = 0.f;
        if (cnt == 2) {
#pragma unroll
            for (int l = 0; l < 3; ++l) {
                float4 v0 = *(const float4*)(base + l * LSTR);
                float4 v1 = *(const float4*)(base + l * LSTR + 4);
                float4 v2 = *(const float4*)(base + l * LSTR + DD);
                float4 v3 = *(const float4*)(base + l * LSTR + DD + 4);
                a[0] += v0.x + v2.x; a[1] += v0.y + v2.y;
                a[2] += v0.z + v2.z; a[3] += v0.w + v2.w;
                a[4] += v1.x + v3.x; a[5] += v1.y + v3.y;
                a[6] += v1.z + v3.z; a[7] += v1.w + v3.w;
            }
        } else {
            for (int l = 0; l < 3; ++l)
                for (int ti = 0; ti < cnt; ++ti) {
                    const float* p = base + l * LSTR + (size_t)ti * DD;
                    float4 v0 = *(const float4*)(p);
                    float4 v1 = *(const float4*)(p + 4);
                    a[0] += v0.x; a[1] += v0.y; a[2] += v0.z; a[3] += v0.w;
                    a[4] += v1.x; a[5] += v1.y; a[6] += v1.z; a[7] += v1.w;
                }
        }
        float inv = 1.0f / (3.0f * (float)(cnt > 0 ? cnt : 1));
#pragma unroll
        for (int q = 0; q < 8; q++) r[q] = (_Float16)(a[q] * inv);
    } else {
        int ci = cap_inds[bw];
#pragma unroll
        for (int q = 0; q < 8; q++) {
            int c = (d8 - 96) * 8 + q;   // col 768+c
            r[q] = (c < CAP_DIM) ? (_Float16)cap_table[ci * CAP_DIM + c] : (_Float16)0.f;
        }
    }
    *(f16x8*)(x + (size_t)bw * KPAD + d8 * 8) = r;
}

// ---------------- K2: FUSED gemm+LSTM ---------------------------------------
// grid 128 (dir*64 + b), block 320 (5 waves).
// Wave 0: recurrence on chunk ch (readlane h-broadcast, permlane32 exchange).
// Waves 1-4: MFMA-compute chunk ch+1's gates (M=64,N=80,K=800; bias folded,
// cols permuted) directly into the LDS ping-pong buffer.
__device__ __forceinline__ float xchg32(float v) {
    unsigned int a = __float_as_uint(v);
    uint2v r = __builtin_amdgcn_permlane32_swap(a, a, false, false);
    return __uint_as_float(r[0] ^ r[1] ^ a);   // partner lane's value (lane ^ 32)
}

__global__ __launch_bounds__(320) void k_lstm(
    const _Float16* __restrict__ x, const _Float16* __restrict__ wp,
    const float* __restrict__ bias_f, const float* __restrict__ bias_b,
    const float* __restrict__ whh_f, const float* __restrict__ whh_b,
    float* __restrict__ out)
{
    __shared__ float gbuf[2][64 * G4];   // 2 x 20 KB ping-pong (permuted cols)
    int dir  = blockIdx.x >> 6;
    int b    = blockIdx.x & 63;
    int t    = threadIdx.x;
    int wv   = t >> 6;
    int lane = t & 63;

    // ---- gemm-side per-lane constants (waves 1-4) ----
    int mtile = wv - 1;                          // 0..3
    int col   = lane & 15;                       // C/D col (dir-local gate % 16)
    int koff  = (lane >> 4) * 8;
    const _Float16* bp = wp + (size_t)(dir * G4 + col) * KPAD + koff;
    float bias_v[5];
    if (wv > 0) {
#pragma unroll
        for (int nf = 0; nf < 5; nf++)
            bias_v[nf] = (dir ? bias_b : bias_f)[nf * 16 + col];
    }

    // ---- recurrence-side per-lane constants (wave 0) ----
    const float* whh = dir ? whh_b : whh_f;
    int j = lane & 31; if (j > 19) j = 19;
    bool low = lane < 32;
    float mm = low ? 1.f : 2.f;
    float aa = low ? 0.f : -1.f;
    int coff = low ? (40 + 2 * j) : (2 * j);     // (f,o) | (i,g) pair
    float w0[HH], w1[HH];
    if (wv == 0) {
        int r0 = low ? (20 + j) : j;
        int r1 = low ? (60 + j) : (40 + j);
#pragma unroll
        for (int k = 0; k < HH; k++) {
            w0[k] = whh[r0 * HH + k];
            w1[k] = whh[r1 * HH + k];
        }
    }

#define COMPUTE_CHUNK(CH, BUF) do {                                             \
    int base_w = dir ? (192 - (CH) * 64) : (CH) * 64;                           \
    int arow = b * 256 + base_w + mtile * 16 + (lane & 15);                     \
    const _Float16* ap = x + (size_t)arow * KPAD + koff;                        \
    f32x4 acc[5];                                                               \
    _Pragma("unroll")                                                           \
    for (int nf = 0; nf < 5; nf++)                                              \
        _Pragma("unroll")                                                       \
        for (int r = 0; r < 4; r++) acc[nf][r] = 0.f;                           \
    for (int k0 = 0; k0 < KPAD; k0 += 32) {                                     \
        f16x8 af = *(const f16x8*)(ap + k0);                                    \
        _Pragma("unroll")                                                       \
        for (int nf = 0; nf < 5; nf++) {                                        \
            f16x8 bf = *(const f16x8*)(bp + (size_t)nf * 16 * KPAD + k0);       \
            acc[nf] = __builtin_amdgcn_mfma_f32_16x16x32_f16(af, bf, acc[nf], 0, 0, 0); \
        }                                                                       \
    }                                                                           \
    int lrow = mtile * 16 + (lane >> 4) * 4;                                    \
    _Pragma("unroll")                                                           \
    for (int nf = 0; nf < 5; nf++) {                                            \
        int g = nf * 16 + col;                                                  \
        int pcol = (g % 40) * 2 + (g / 40);                                     \
        _Pragma("unroll")                                                       \
        for (int r = 0; r < 4; r++)                                             \
            gbuf[BUF][(lrow + r) * G4 + pcol] = acc[nf][r] + bias_v[nf];        \
    }                                                                           \
} while (0)

    // prologue: chunk 0 -> gbuf[0]
    if (wv > 0) COMPUTE_CHUNK(0, 0);
    __syncthreads();

    float h = 0.f, c = 0.f;
    int w = dir ? (WW - 1) : 0;
    int stepd = dir ? -1 : 1;

    for (int ch = 0; ch < 4; ++ch) {
        int cb = ch & 1;
        if (wv > 0) {
            if (ch + 1 < 4) COMPUTE_CHUNK(ch + 1, cb ^ 1);
        } else {
            int base = dir ? (192 - ch * 64) : ch * 64;
            float2 pre = *(const float2*)(&gbuf[cb][(w - base) * G4 + coff]);
            for (int sl = 0; sl < 64; ++sl) {
                int wn = w + stepd;
                float2 nxt = make_float2(0.f, 0.f);
                if (sl < 63)
                    nxt = *(const float2*)(&gbuf[cb][(wn - base) * G4 + coff]);
                float a0a = pre.x, a0b = 0.f, a1a = pre.y, a1b = 0.f;
#pragma unroll
                for (int k = 0; k < 10; k++) {
                    float hk  = __uint_as_float(__builtin_amdgcn_readlane(__float_as_uint(h), k));
                    float hk2 = __uint_as_float(__builtin_amdgcn_readlane(__float_as_uint(h), k + 10));
                    a0a = fmaf(hk,  w0[k],      a0a);
                    a1a = fmaf(hk,  w1[k],      a1a);
                    a0b = fmaf(hk2, w0[k + 10], a0b);
                    a1b = fmaf(hk2, w1[k + 10], a1b);
                }
                float a0 = a0a + a0b, a1 = a1a + a1b;
                float u0 = 1.f / (1.f + __expf(-a0));          // sig(f) | sig(i)
                float uu = 1.f / (1.f + __expf(-mm * a1));
                float u1 = fmaf(uu, mm, aa);                   // sig(o) | tanh(g)
                float p  = u0 * u1;
                float ps = xchg32(p);                          // low gets sig(i)*tanh(g)
                c = fmaf(u0, c, ps);
                float tc = fmaf(2.f, 1.f / (1.f + __expf(-2.f * c)), -1.f);
                h = u1 * tc;
                if (lane < HH)
                    out[((size_t)b * WW + w) * (2 * HH) + dir * HH + lane] = h;
                pre = nxt;
                w = wn;
            }
        }
        __syncthreads();
    }
#undef COMPUTE_CHUNK
}

extern "C" void kernel_launch(void* const* d_in, const int* in_sizes, int n_in,
                              void* d_out, int out_size, void* d_ws, size_t ws_size,
                              hipStream_t stream) {
    const float* hiddens   = (const float*)d_in[0];
    const int*   bert2toks = (const int*)d_in[1];
    const int*   cap_inds  = (const int*)d_in[2];
    const float* cap_table = (const float*)d_in[3];
    const float* w_ih_f    = (const float*)d_in[4];
    const float* w_hh_f    = (const float*)d_in[5];
    const float* b_f       = (const float*)d_in[6];
    const float* w_ih_b    = (const float*)d_in[7];
    const float* w_hh_b    = (const float*)d_in[8];
    const float* b_b       = (const float*)d_in[9];
    float* out = (float*)d_out;

    _Float16* wpad = (_Float16*)((char*)d_ws + WP_OFF);
    int2*     seg  = (int2*)((char*)d_ws + SEG_OFF);
    _Float16* x    = (_Float16*)((char*)d_ws + X_OFF);

    k_prep<<<NOUT + BB, 256, 0, stream>>>(w_ih_f, w_ih_b, bert2toks, wpad, seg);
    k_mean<<<(BB * WW * 100) / 256, 256, 0, stream>>>(hiddens, seg, cap_inds, cap_table, x);
    k_lstm<<<128, 320, 0, stream>>>(x, wpad, b_f, b_b, w_hh_f, w_hh_b, out);
}